// Round 8
// baseline (316.160 us; speedup 1.0000x reference)
//
#include <hip/hip_runtime.h>
#include <cstdint>
#include <cstddef>

// Problem constants: B=64, C=3, H=W=64, F=96, K=8, h=w=32, C0=6, P=h*w=1024
// params channels: a[0:6) b[6:12) logpi[12:60) mu[60:108) s[108:156)

typedef unsigned short u16;
typedef __attribute__((ext_vector_type(8))) short short8;
typedef __attribute__((ext_vector_type(4))) float f32x4;
typedef __attribute__((ext_vector_type(4))) unsigned int u32x4;

__device__ __forceinline__ float sigm(float x){ return 1.0f/(1.0f+__expf(-x)); }

__device__ __forceinline__ u16 f2bf(float f){
    unsigned int u = __float_as_uint(f);
    u += 0x7fffu + ((u >> 16) & 1u);
    return (u16)(u >> 16);
}
__device__ __forceinline__ float bf2f(u16 v){
    unsigned int u = ((unsigned int)v) << 16;
    return __uint_as_float(u);
}

// async global->LDS DMA, 16B per lane; LDS dest must be wave-uniform base (+lane*16 implied)
__device__ __forceinline__ void dma16(const u16* g, u16* l){
    __builtin_amdgcn_global_load_lds(
        (const __attribute__((address_space(1))) void*)g,
        (__attribute__((address_space(3))) void*)l,
        16, 0, 0);
}

// v_exp_f32 computes 2^x; Q is prescaled by log2(e)/sqrt(96) so this is exp(QK/sqrt(96)).
__device__ __forceinline__ float ex2(float x){
    float r; asm("v_exp_f32 %0, %1" : "=v"(r) : "v"(x)); return r;
}
__device__ __forceinline__ unsigned cvtpk(float lo, float hi){
    unsigned r; asm("v_cvt_pk_bf16_f32 %0, %1, %2" : "=v"(r) : "v"(lo), "v"(hi)); return r;
}
__device__ __forceinline__ void plswap32(unsigned &a, unsigned &b){
    asm("v_permlane32_swap_b32 %0, %1" : "+v"(a), "+v"(b));
}
__device__ __forceinline__ void plswap16(unsigned &a, unsigned &b){
    asm("v_permlane16_swap_b32 %0, %1" : "+v"(a), "+v"(b));
}

// In-register softmax+pack (verified round 1): S[t][r] = scores (q=cc, k=16t+4gg+r).
// Produces PV A-fragments PA[kk]: lane(cc,gg) holds bf16 P[q=cc][k=32kk+8gg+j].
#define SOFTPACK(S, LACC, PA) do { \
    unsigned pk_[4][2]; \
    _Pragma("unroll") \
    for (int t=0;t<4;++t){ \
        float e0 = ex2(S[t][0]); \
        float e1 = ex2(S[t][1]); \
        float e2 = ex2(S[t][2]); \
        float e3 = ex2(S[t][3]); \
        LACC += (e0+e1)+(e2+e3); \
        pk_[t][0] = cvtpk(e0,e1); \
        pk_[t][1] = cvtpk(e2,e3); \
    } \
    _Pragma("unroll") \
    for (int kk=0;kk<2;++kk){ \
        unsigned a0 = pk_[2*kk][0], b0 = pk_[2*kk+1][0]; \
        unsigned a1 = pk_[2*kk][1], b1 = pk_[2*kk+1][1]; \
        plswap32(a0,b0); plswap16(a0,b0); \
        plswap32(a1,b1); plswap16(a1,b1); \
        u32x4 dw_; dw_[0]=a0; dw_[1]=a1; dw_[2]=b0; dw_[3]=b1; \
        PA[kk] = __builtin_bit_cast(short8, dw_); \
    } \
} while(0)

// LN-apply while building an MFMA A-fragment: 8 channels at pixel p, channel base c0.
__device__ __forceinline__ short8 ln_frag(const u16* __restrict__ xg,
    const float* __restrict__ gt, const float* __restrict__ bt,
    int p, int c0, float mu, float rr)
{
    short8 x8 = *reinterpret_cast<const short8*>(xg + (size_t)p*96 + c0);
    const float* gp = gt + (size_t)p*96 + c0;
    const float* bp = bt + (size_t)p*96 + c0;
    short8 o;
    #pragma unroll
    for (int j=0;j<8;++j){
        float ag = rr*gp[j];
        o[j] = (short)f2bf(bf2f((u16)x8[j])*ag + (bp[j] - mu*ag));
    }
    return o;
}

// ---------------- mega-prep: MFMA-conv1 + all weight repacks (fragment-slot linear order,
// DMA-able) + LN transposes + initlog.
__global__ __launch_bounds__(256) void k_prep(
    const float* __restrict__ z, const float* __restrict__ c1w, const float* __restrict__ c1b,
    const float* __restrict__ gw, const float* __restrict__ c2w,
    const float* __restrict__ qkvw, const float* __restrict__ pw,
    const float* __restrict__ ln1g, const float* __restrict__ ln1b,
    const float* __restrict__ ln2g, const float* __restrict__ ln2b,
    const float* __restrict__ logdf,
    u16* __restrict__ x1b,
    u16* __restrict__ Wg, u16* __restrict__ W2,
    u16* __restrict__ Wqkv, u16* __restrict__ Wproj,
    float* __restrict__ gt1, float* __restrict__ bt1,
    float* __restrict__ gt2, float* __restrict__ bt2,
    float* __restrict__ outlog)
{
    int blk = blockIdx.x;
    int tid = threadIdx.x;
    __shared__ float tin[6][6][34];             // conv1 halo tile
    __shared__ __align__(16) u16 Wc[96][72];    // conv1 weights bf16, K padded 54->72
    __shared__ __align__(16) u16 imc[128][72];  // im2col bf16

    if (blk < 512){
        // ---- conv1 as MFMA im2col GEMM: 128 px x 96 oc, K=54 padded to 64
        int b  = blk >> 3;
        int pg = blk & 7;
        int r0 = pg*4;
        for (int e = tid; e < 96*72; e += 256){
            int oc = e/72, k = e%72;
            Wc[oc][k] = (k < 54) ? f2bf(c1w[oc*54 + k]) : (u16)0;
        }
        for (int idx = tid; idx < 6*6*34; idx += 256){
            int c = idx/204, rem = idx%204;
            int rr = rem/34, q = rem%34;
            int ii = r0 - 1 + rr, jj = q - 1;
            float v = 0.f;
            if ((unsigned)ii < 32u && (unsigned)jj < 32u){
                if (c < 3) v = z[((b*3+c)*64 + 2*ii)*64 + (2*jj+1)];        // p01
                else       v = z[((b*3+(c-3))*64 + (2*ii+1))*64 + 2*jj];    // p10
            }
            tin[c][rr][q] = v;
        }
        __syncthreads();
        for (int e = tid; e < 128*72; e += 256){
            int px = e/72, k = e%72;
            float v = 0.f;
            if (k < 54){
                int c = k/9, rr = (k%9)/3, dcc = k%3;
                v = tin[c][(px>>5)+rr][(px&31)+dcc];
            }
            imc[px][k] = f2bf(v);
        }
        __syncthreads();

        int w = tid >> 6, lane = tid & 63;
        int cc = lane & 15, gg = lane >> 4;
        f32x4 acc[2][6];
        #pragma unroll
        for (int u=0;u<2;++u)
            #pragma unroll
            for (int t=0;t<6;++t) acc[u][t] = (f32x4){0.f,0.f,0.f,0.f};

        #pragma unroll
        for (int ks=0; ks<2; ++ks){
            short8 a0 = *reinterpret_cast<const short8*>(&imc[w*32 + cc     ][ks*32 + 8*gg]);
            short8 a1 = *reinterpret_cast<const short8*>(&imc[w*32 + 16 + cc][ks*32 + 8*gg]);
            #pragma unroll
            for (int t=0; t<6; ++t){
                short8 bb = *reinterpret_cast<const short8*>(&Wc[t*16+cc][ks*32 + 8*gg]);
                acc[0][t] = __builtin_amdgcn_mfma_f32_16x16x32_bf16(a0, bb, acc[0][t], 0,0,0);
                acc[1][t] = __builtin_amdgcn_mfma_f32_16x16x32_bf16(a1, bb, acc[1][t], 0,0,0);
            }
        }

        #pragma unroll
        for (int u=0;u<2;++u){
            int p0 = pg*128 + w*32 + u*16 + gg*4;
            #pragma unroll
            for (int t=0;t<6;++t){
                int oc = t*16+cc;
                float bv = c1b[oc];
                #pragma unroll
                for (int r=0;r<4;++r)
                    x1b[((size_t)(b*1024) + p0 + r)*96 + oc] = f2bf(acc[u][t][r] + bv);
            }
        }
    } else if (blk < 1160){
        // gconv weights, fragment-slot order: idx = ((tap*2+obk)*18 + t*3+ks)*512 + lane*8 + j
        int idx = (blk-512)*256 + tid;                // < 165888
        int j = idx & 7;
        int lane = (idx >> 3) & 63;
        int fo = idx >> 9;
        int frag = fo % 18;
        int tob = fo / 18;
        int obk = tob & 1, tap = tob >> 1;
        int t = frag/3, ks = frag%3;
        int cc = lane & 15, gg = lane >> 4;
        int ocp = obk*96 + t*16 + cc;                 // packed-paired row
        int r2 = ocp%96, isB = r2/48, i2 = r2%48;
        int oc = (ocp/96)*48 + i2 + isB*96;
        int ic = ks*32 + 8*gg + j;
        Wg[idx] = f2bf(gw[(size_t)(oc*96+ic)*9 + tap]);
    } else if (blk < 1700){
        // conv2 weights: idx = ((tap*2+obk)*15 + t*3+ks)*512 + lane*8 + j
        int idx = (blk-1160)*256 + tid;               // < 138240
        int j = idx & 7;
        int lane = (idx >> 3) & 63;
        int fo = idx >> 9;
        int frag = fo % 15;
        int tob = fo / 15;
        int obk = tob & 1, tap = tob >> 1;
        int t = frag/3, ks = frag%3;
        int cc = lane & 15, gg = lane >> 4;
        int oc = obk*80 + t*16 + cc;
        int ic = ks*32 + 8*gg + j;
        W2[idx] = (oc < 156) ? f2bf(c2w[(size_t)(oc*96+ic)*9 + tap]) : (u16)0;
    } else if (blk < 1808){
        // qkv weights: idx = (obk*27 + t*3+ks)*512 + lane*8 + j
        int idx = (blk-1700)*256 + tid;               // < 27648
        int j = idx & 7;
        int lane = (idx >> 3) & 63;
        int fo = idx >> 9;
        int frag = fo % 27;
        int obk = fo / 27;
        int t = frag/3, ks = frag%3;
        int cc = lane & 15, gg = lane >> 4;
        int n = obk*144 + t*16 + cc;
        int ic = ks*32 + 8*gg + j;
        Wqkv[idx] = f2bf(qkvw[(size_t)n*96 + ic]);
    } else if (blk < 1880){
        // proj weights (packed-paired): idx = (obk*18 + t*3+ks)*512 + lane*8 + j
        int idx = (blk-1808)*256 + tid;               // < 18432
        int j = idx & 7;
        int lane = (idx >> 3) & 63;
        int fo = idx >> 9;
        int frag = fo % 18;
        int obk = fo / 18;
        int t = frag/3, ks = frag%3;
        int cc = lane & 15, gg = lane >> 4;
        int ocp = obk*96 + t*16 + cc;
        int r2 = ocp%96, isB = r2/48, i2 = r2%48;
        int oc = obk*48 + i2 + isB*96;
        int ic = ks*32 + 8*gg + j;
        Wproj[idx] = f2bf(pw[(size_t)oc*96 + ic]);
    } else if (blk < 2264){
        int idx = (blk-1880)*256 + tid;               // < 98304
        int c = idx >> 10, p = idx & 1023;
        gt1[p*96 + c] = ln1g[idx];
    } else if (blk < 2648){
        int idx = (blk-2264)*256 + tid;
        int c = idx >> 10, p = idx & 1023;
        bt1[p*96 + c] = ln1b[idx];
    } else if (blk < 3032){
        int idx = (blk-2648)*256 + tid;
        int c = idx >> 10, p = idx & 1023;
        gt2[p*96 + c] = ln2g[idx];
    } else if (blk < 3416){
        int idx = (blk-3032)*256 + tid;
        int c = idx >> 10, p = idx & 1023;
        bt2[p*96 + c] = ln2b[idx];
    } else {
        if (tid < 64) outlog[tid] = logdf[tid];
    }
}

// ---------------- gated conv v2: input tile staged ONCE into LDS (fragment-major, rows
// pblk*4-1..+4), taps read LDS instead of 9x global. Weight dbuf DMA, 1 barrier/tap.
// LDS 73.8 KB -> 2 blocks/CU. Global A-traffic drops ~6x.
__global__ __launch_bounds__(256,2) void k_gconv(const u16* __restrict__ Xpb,
    const u16* __restrict__ Wt, const float* __restrict__ bias,
    u16* __restrict__ outb, float* __restrict__ partials)
{
    int blk  = blockIdx.x;
    int obk  = blk & 1;
    int pblk = (blk >> 1) & 7;
    int b    = blk >> 4;
    int tid  = threadIdx.x;
    int w = tid >> 6, lane = tid & 63;
    int cc = lane & 15, gg = lane >> 4;

    __shared__ __align__(16) u16 As[18432];       // input tile [6 rows][3 ks][4 gg][32 col][8]
    __shared__ __align__(16) u16 Ws[2][9216];     // 18 frags * 512 per tap
    __shared__ float red[8];

    const u16* xb = Xpb + (size_t)b*1024*96;

    // stage input tile (zero-fill OOB rows = conv zero-pad)
    {
        int rowbase = pblk*4 - 1;
        #pragma unroll
        for (int i=0;i<9;++i){
            int e = tid + 256*i;                  // 0..2303 exactly
            int px = e/12, sub = e%12;
            int ks = sub >> 2, g2 = sub & 3;
            int lr = px >> 5, col = px & 31;
            int grow = rowbase + lr;
            short8 v = {0,0,0,0,0,0,0,0};
            if ((unsigned)grow < 32u)
                v = *reinterpret_cast<const short8*>(xb + (size_t)(grow*32+col)*96 + ks*32 + 8*g2);
            *reinterpret_cast<short8*>(As + ((size_t)((lr*3+ks)*4+g2)*32 + col)*8) = v;
        }
    }
    {   // stage tap 0 weights
        const u16* src = Wt + (size_t)obk*9216;
        #pragma unroll
        for (int i=0;i<5;++i){
            int c = tid + 256*i;
            if (c < 1152) dma16(src + (size_t)c*8, Ws[0] + (size_t)(w*64+256*i)*8);
        }
    }

    f32x4 acc[2][6];
    #pragma unroll
    for (int u=0;u<2;++u)
        #pragma unroll
        for (int t=0;t<6;++t) acc[u][t] = (f32x4){0.f,0.f,0.f,0.f};

    int base = pblk*128 + w*32;

    for (int tap=0; tap<9; ++tap){
        __syncthreads();                          // drains vmcnt+lgkm: Ws[tap&1] + As complete
        if (tap < 8){
            const u16* src = Wt + (size_t)((tap+1)*2 + obk)*9216;
            int nb = (tap+1)&1;
            #pragma unroll
            for (int i=0;i<5;++i){
                int c = tid + 256*i;
                if (c < 1152) dma16(src + (size_t)c*8, Ws[nb] + (size_t)(w*64+256*i)*8);
            }
        }
        const u16* Wc = Ws[tap&1];
        int dr = tap/3 - 1, dc = tap%3 - 1;

        int lrr = w + 1 + dr;                     // 0..5, always staged (zero if OOB row)
        int jj0 = cc + dc, jj1 = cc + 16 + dc;
        bool v0 = ((unsigned)jj0 < 32u);
        bool v1 = ((unsigned)jj1 < 32u);

        #pragma unroll
        for (int ks=0; ks<3; ++ks){
            const u16* ab = As + ((size_t)((lrr*3+ks)*4 + gg)*32)*8;
            short8 a0 = {0,0,0,0,0,0,0,0};
            short8 a1 = {0,0,0,0,0,0,0,0};
            if (v0) a0 = *reinterpret_cast<const short8*>(ab + jj0*8);
            if (v1) a1 = *reinterpret_cast<const short8*>(ab + jj1*8);
            #pragma unroll
            for (int t=0; t<6; ++t){
                short8 bb = *reinterpret_cast<const short8*>(Wc + ((size_t)(t*3+ks)*64 + lane)*8);
                acc[0][t] = __builtin_amdgcn_mfma_f32_16x16x32_bf16(a0, bb, acc[0][t], 0,0,0);
                acc[1][t] = __builtin_amdgcn_mfma_f32_16x16x32_bf16(a1, bb, acc[1][t], 0,0,0);
            }
        }
    }

    float s = 0.f, ssq = 0.f;
    #pragma unroll
    for (int u=0;u<2;++u){
        int p0 = base + u*16 + gg*4;
        #pragma unroll
        for (int t=0;t<3;++t){
            int ocA = obk*48 + t*16+cc;
            float ba = bias[ocA], bbv = bias[ocA+96];
            #pragma unroll
            for (int r=0;r<4;++r){
                float res = bf2f(Xpb[((size_t)b*1024 + p0+r)*96 + ocA]);
                float va = acc[u][t][r]   + ba;
                float vb = acc[u][t+3][r] + bbv;
                float v = res + va*sigm(vb);
                outb[((size_t)b*1024 + p0+r)*96 + ocA] = f2bf(v);
                s += v; ssq += v*v;
            }
        }
    }
    #pragma unroll
    for (int o=32;o>0;o>>=1){ s += __shfl_down(s,o,64); ssq += __shfl_down(ssq,o,64); }
    if (lane==0){ red[w]=s; red[4+w]=ssq; }
    __syncthreads();
    if (tid==0){
        int slot = b*16 + pblk*2 + obk;
        partials[slot*2+0] = red[0]+red[1]+red[2]+red[3];
        partials[slot*2+1] = red[4]+red[5]+red[6]+red[7];
    }
}

// ---------------- qkv with inline LN1: OC 288 split across 2 blocks of 144, grid 1024.
__global__ __launch_bounds__(256,4) void k_qkvm(const u16* __restrict__ Xg,
    const float* __restrict__ gt, const float* __restrict__ bt,
    const float* __restrict__ part,
    const u16* __restrict__ Wt, const float* __restrict__ bias,
    u16* __restrict__ Qb, u16* __restrict__ Kf, u16* __restrict__ Vf)
{
    int blk  = blockIdx.x;
    int obk  = blk & 1;
    int pblk = (blk >> 1) & 7;
    int b    = blk >> 4;
    int tid  = threadIdx.x;
    int w = tid >> 6, lane = tid & 63;
    int cc = lane & 15, gg = lane >> 4;
    const float scale = 0.14724445f;   // log2(e)/sqrt(96)

    __shared__ __align__(16) u16 Ws[13824];       // 27 frags * 512
    {
        const u16* src = Wt + (size_t)obk*13824;
        #pragma unroll
        for (int i=0;i<7;++i){
            int c = tid + 256*i;
            if (c < 1728) dma16(src + (size_t)c*8, Ws + (size_t)(w*64+256*i)*8);
        }
    }

    float sS=0.f, sQ=0.f;
    #pragma unroll
    for (int i=0;i<16;++i){ sS += part[(b*16+i)*2]; sQ += part[(b*16+i)*2+1]; }
    float mu = sS/98304.f;
    float rr = rsqrtf(sQ/98304.f - mu*mu + 1e-5f);

    f32x4 acc[2][9];
    #pragma unroll
    for (int u=0;u<2;++u)
        #pragma unroll
        for (int t=0;t<9;++t) acc[u][t] = (f32x4){0.f,0.f,0.f,0.f};

    int base = pblk*128 + w*32;
    const u16* xg = Xg + (size_t)b*1024*96;
    __syncthreads();                              // Ws DMA complete

    #pragma unroll
    for (int ks=0; ks<3; ++ks){
        int c0 = ks*32 + 8*gg;
        short8 a0 = ln_frag(xg, gt, bt, base+cc,    c0, mu, rr);
        short8 a1 = ln_frag(xg, gt, bt, base+cc+16, c0, mu, rr);
        #pragma unroll
        for (int t=0; t<9; ++t){
            short8 bb = *reinterpret_cast<const short8*>(Ws + ((size_t)(t*3+ks)*64 + lane)*8);
            acc[0][t] = __builtin_amdgcn_mfma_f32_16x16x32_bf16(a0, bb, acc[0][t], 0,0,0);
            acc[1][t] = __builtin_amdgcn_mfma_f32_16x16x32_bf16(a1, bb, acc[1][t], 0,0,0);
        }
    }

    #pragma unroll
    for (int u=0;u<2;++u){
        int p0 = base + u*16 + gg*4;
        #pragma unroll
        for (int t=0;t<9;++t){
            int n = obk*144 + t*16+cc;
            float bv = bias[n];
            #pragma unroll
            for (int r=0;r<4;++r){
                int p = p0 + r;
                float av = acc[u][t][r] + bv;
                if (n < 96){
                    Qb[((size_t)(b*1024+p))*96 + n] = f2bf(av*scale);
                } else if (n < 192){
                    int f = n-96;
                    int jt = p>>6, t16 = (p>>4)&3, ccs = p&15;
                    int ks = f>>5, ggs = (f>>3)&3, j = f&7;
                    Kf[(size_t)(b*16+jt)*6144 + (size_t)(((t16*3+ks)*4+ggs)*16+ccs)*8 + j] = f2bf(av);
                } else {
                    int f = n-192;
                    int jt = p>>6, kl = p&63;
                    int kk = kl>>5, ggs = (kl>>3)&3, j = kl&7;
                    int ft = f>>4, ccs = f&15;
                    Vf[(size_t)(b*16+jt)*6144 + (size_t)(((ft*2+kk)*4+ggs)*16+ccs)*8 + j] = f2bf(av);
                }
            }
        }
    }
}

// ---------------- FUSED flash attention + proj (unchanged from round 7).
__global__ __launch_bounds__(256,2) void k_attnproj(const u16* __restrict__ Qb,
    const u16* __restrict__ Kf, const u16* __restrict__ Vf,
    const u16* __restrict__ Wpg, const float* __restrict__ pbias,
    const u16* __restrict__ Xg, const float* __restrict__ gt, const float* __restrict__ bt,
    const float* __restrict__ part1,
    u16* __restrict__ outb, float* __restrict__ partials)
{
    int qt = blockIdx.x >> 6;       // 0..7
    int b  = blockIdx.x & 63;
    int tid = threadIdx.x;
    int w  = tid >> 6;
    int lane = tid & 63;
    int cc = lane & 15;
    int gg = lane >> 4;

    __shared__ __align__(16) u16 SM[36864];   // 73728 B: phase1 Ks[3][6144]+Vs[3][6144];
                                              // phase2 Wp[18432] + Ot[128][104]
    __shared__ float red[16];

    u16* Ksb = SM;              // [3][6144]
    u16* Vsb = SM + 18432;      // [3][6144]
    u16* Wp  = SM;              // phase 2 overlay (Ks region)
    u16* Ot  = SM + 18432;      // phase 2 overlay (Vs region): 128 rows x 104

    // LN1 stats (needed in phase-2 epilogue; cheap, do up front)
    float sS=0.f, sQ=0.f;
    #pragma unroll
    for (int i=0;i<16;++i){ sS += part1[(b*16+i)*2]; sQ += part1[(b*16+i)*2+1]; }
    float mu1 = sS/98304.f;
    float rr1 = rsqrtf(sQ/98304.f - mu1*mu1 + 1e-5f);

    int q0 = qt*128 + w*32;

    short8 qf[2][3];
    {
        const u16* qr0 = Qb + ((size_t)(b*1024 + q0 + cc))*96;
        #pragma unroll
        for (int ks=0; ks<3; ++ks){
            qf[0][ks] = *reinterpret_cast<const short8*>(qr0 + ks*32 + 8*gg);
            qf[1][ks] = *reinterpret_cast<const short8*>(qr0 + (size_t)16*96 + ks*32 + 8*gg);
        }
    }

    f32x4 Oacc[2][6];
    #pragma unroll
    for (int u=0;u<2;++u)
        #pragma unroll
        for (int ft=0; ft<6; ++ft) Oacc[u][ft] = (f32x4){0.f,0.f,0.f,0.f};
    float l_acc[2] = {0.f, 0.f};

    const u16* Kb0 = Kf + (size_t)(b*16)*6144;
    const u16* Vb0 = Vf + (size_t)(b*16)*6144;

    #pragma unroll
    for (int i=0;i<3;++i){
        size_t c8 = (size_t)(tid + 256*i)*8;
        size_t l8 = (size_t)(w*64 + 256*i)*8;
        dma16(Kb0 + c8, Ksb + l8);
        dma16(Vb0 + c8, Vsb + l8);
    }
    #pragma unroll
    for (int i=0;i<3;++i){
        size_t c8 = (size_t)(6144 + (tid + 256*i)*8);
        size_t l8 = (size_t)(w*64 + 256*i)*8;
        dma16(Kb0 + c8, Ksb + 6144 + l8);
        dma16(Vb0 + c8, Vsb + 6144 + l8);
    }

    for (int jt=0; jt<16; ++jt){
        if (jt < 15) asm volatile("s_waitcnt vmcnt(6)" ::: "memory");
        else         asm volatile("s_waitcnt vmcnt(0)" ::: "memory");
        __builtin_amdgcn_s_barrier();
        __builtin_amdgcn_sched_barrier(0);

        if (jt < 14){
            const u16* kn = Kb0 + (size_t)(jt+2)*6144;
            const u16* vn = Vb0 + (size_t)(jt+2)*6144;
            u16* kd = Ksb + (size_t)((jt+2)%3)*6144;
            u16* vd = Vsb + (size_t)((jt+2)%3)*6144;
            #pragma unroll
            for (int i=0;i<3;++i){
                size_t c8 = (size_t)(tid + 256*i)*8;
                size_t l8 = (size_t)(w*64 + 256*i)*8;
                dma16(kn + c8, kd + l8);
                dma16(vn + c8, vd + l8);
            }
        }

        const u16* Kc = Ksb + (size_t)(jt%3)*6144;
        const u16* Vc = Vsb + (size_t)(jt%3)*6144;

        f32x4 S0[4], S1[4];
        #pragma unroll
        for (int t=0;t<4;++t){ S0[t] = (f32x4){0.f,0.f,0.f,0.f}; S1[t] = (f32x4){0.f,0.f,0.f,0.f}; }

        __builtin_amdgcn_s_setprio(1);
        #pragma unroll
        for (int ks=0; ks<3; ++ks){
            #pragma unroll
            for (int t=0; t<4; ++t){
                short8 kb = *reinterpret_cast<const short8*>(Kc + ((t*3+ks)*64 + lane)*8);
                S0[t] = __builtin_amdgcn_mfma_f32_16x16x32_bf16(kb, qf[0][ks], S0[t], 0,0,0);
                S1[t] = __builtin_amdgcn_mfma_f32_16x16x32_bf16(kb, qf[1][ks], S1[t], 0,0,0);
            }
        }
        __builtin_amdgcn_s_setprio(0);

        short8 pa0[2], pa1[2];
        SOFTPACK(S0, l_acc[0], pa0);
        SOFTPACK(S1, l_acc[1], pa1);

        __builtin_amdgcn_s_setprio(1);
        #pragma unroll
        for (int kk=0; kk<2; ++kk){
            #pragma unroll
            for (int ft=0; ft<6; ++ft){
                short8 vb = *reinterpret_cast<const short8*>(Vc + ((ft*2+kk)*64 + lane)*8);
                Oacc[0][ft] = __builtin_amdgcn_mfma_f32_16x16x32_bf16(pa0[kk], vb, Oacc[0][ft], 0,0,0);
                Oacc[1][ft] = __builtin_amdgcn_mfma_f32_16x16x32_bf16(pa1[kk], vb, Oacc[1][ft], 0,0,0);
            }
        }
        __builtin_amdgcn_s_setprio(0);
    }

    // ---- phase transition: all waves done reading K/V regions
    __syncthreads();

    // Wproj DMA into Ks region: 2304 * 16B = 36864 B, 9 dma16/thread, exact
    #pragma unroll
    for (int i=0;i<9;++i){
        int c = tid + 256*i;
        dma16(Wpg + (size_t)c*8, Wp + (size_t)(w*64+256*i)*8);
    }

    // O (x 1/l) -> Ot[row=local pixel][col=channel], rows w*32..+31 are wave-private
    #pragma unroll
    for (int u=0;u<2;++u){
        float lv = l_acc[u];
        lv += __shfl_xor(lv, 16, 64);
        lv += __shfl_xor(lv, 32, 64);
        float linv[4];
        #pragma unroll
        for (int r=0;r<4;++r) linv[r] = 1.0f / __shfl(lv, 4*gg + r, 64);
        #pragma unroll
        for (int ft=0; ft<6; ++ft)
            #pragma unroll
            for (int r=0; r<4; ++r)
                Ot[(size_t)(w*32 + u*16 + 4*gg + r)*104 + ft*16 + cc]
                    = f2bf(Oacc[u][ft][r]*linv[r]);
    }

    __syncthreads();                               // drains vmcnt+lgkm: Wp + Ot complete

    // ---- proj GEMM from LDS: 128 px x 192 ocp (both halves), acc[2][12]
    f32x4 pacc[2][12];
    #pragma unroll
    for (int u=0;u<2;++u)
        #pragma unroll
        for (int t=0;t<12;++t) pacc[u][t] = (f32x4){0.f,0.f,0.f,0.f};

    #pragma unroll
    for (int ks=0; ks<3; ++ks){
        short8 a0 = *reinterpret_cast<const short8*>(Ot + (size_t)(w*32 + cc     )*104 + ks*32 + 8*gg);
        short8 a1 = *reinterpret_cast<const short8*>(Ot + (size_t)(w*32 + cc + 16)*104 + ks*32 + 8*gg);
        #pragma unroll
        for (int t2=0; t2<12; ++t2){
            int obk = t2/6, tl = t2%6;
            short8 bb = *reinterpret_cast<const short8*>(Wp + ((size_t)(obk*18 + tl*3 + ks)*64 + lane)*8);
            pacc[0][t2] = __builtin_amdgcn_mfma_f32_16x16x32_bf16(a0, bb, pacc[0][t2], 0,0,0);
            pacc[1][t2] = __builtin_amdgcn_mfma_f32_16x16x32_bf16(a1, bb, pacc[1][t2], 0,0,0);
        }
    }

    // ---- epilogue: gated residual + LN1-inline, per-obk partial sums (same part2 layout)
    const u16* resb = Xg + (size_t)b*1024*96;
    float s0=0.f, q0s=0.f, s1=0.f, q1s=0.f;
    #pragma unroll
    for (int u=0;u<2;++u){
        int p0 = qt*128 + w*32 + u*16 + gg*4;
        #pragma unroll
        for (int obk=0;obk<2;++obk){
            #pragma unroll
            for (int tl=0;tl<3;++tl){
                int ocA = obk*48 + tl*16 + cc;
                float ba = pbias[ocA], bbv = pbias[ocA+96];
                #pragma unroll
                for (int r=0;r<4;++r){
                    int pl = p0 + r;
                    float ga = pacc[u][obk*6+tl][r]   + ba;
                    float gb = pacc[u][obk*6+tl+3][r] + bbv;
                    float xv = bf2f(resb[(size_t)pl*96 + ocA]);
                    float res = (xv - mu1)*rr1*gt[(size_t)pl*96 + ocA] + bt[(size_t)pl*96 + ocA];
                    float v = res + ga * sigm(gb);
                    outb[((size_t)b*1024 + pl)*96 + ocA] = f2bf(v);
                    if (obk==0){ s0 += v; q0s += v*v; } else { s1 += v; q1s += v*v; }
                }
            }
        }
    }
    #pragma unroll
    for (int o=32;o>0;o>>=1){
        s0 += __shfl_down(s0,o,64);  q0s += __shfl_down(q0s,o,64);
        s1 += __shfl_down(s1,o,64);  q1s += __shfl_down(q1s,o,64);
    }
    if (lane==0){ red[w*4+0]=s0; red[w*4+1]=q0s; red[w*4+2]=s1; red[w*4+3]=q1s; }
    __syncthreads();
    if (tid==0){
        int slot = b*16 + qt*2;
        partials[(size_t)slot*2+0]     = red[0]+red[4]+red[8]+red[12];
        partials[(size_t)slot*2+1]     = red[1]+red[5]+red[9]+red[13];
        partials[(size_t)(slot+1)*2+0] = red[2]+red[6]+red[10]+red[14];
        partials[(size_t)(slot+1)*2+1] = red[3]+red[7]+red[11]+red[15];
    }
}

// ---------------- FUSED LN2 + conv2 + mixture v2: input tile staged ONCE into LDS with
// LN2 applied AT STAGING (not per-tap — that was round 6's mistake); taps read LDS.
// Weights single-buffered (LDS budget), 2 barriers/tap. Pl overlays As+Wbuf after conv.
// Deletes k_lne (dispatch + 25 MB). LDS 67.6 KB -> 2 blocks/CU.
__global__ __launch_bounds__(256,2) void k_c2mix(const u16* __restrict__ X2,
    const float* __restrict__ gt, const float* __restrict__ bt,
    const float* __restrict__ part2,
    const u16* __restrict__ Wt, const float* __restrict__ bias,
    const float* __restrict__ z, const float* __restrict__ a_ls_p,
    const float* __restrict__ a_b_p, float* __restrict__ out_z, float* __restrict__ out_log)
{
    int blk  = blockIdx.x;
    int pblk = blk & 7;
    int b    = blk >> 3;
    int tid  = threadIdx.x;
    int w = tid >> 6, lane = tid & 63;
    int cc = lane & 15, gg = lane >> 4;

    __shared__ __align__(16) u16 SM[33792];   // As[18432] + Wbuf[15360]; Pl[156][132] overlays
    __shared__ float red[4];
    u16* As   = SM;
    u16* Wbuf = SM + 18432;

    // LN2 stats for batch b (before staging — staging applies LN2)
    float sS=0.f, sQ=0.f;
    #pragma unroll
    for (int i=0;i<16;++i){ sS += part2[(b*16+i)*2]; sQ += part2[(b*16+i)*2+1]; }
    float mu2 = sS/98304.f;
    float rr2 = rsqrtf(sQ/98304.f - mu2*mu2 + 1e-5f);

    const u16* xb2 = X2 + (size_t)b*1024*96;

    // stage input tile with LN2 applied once (zero-fill OOB rows = conv zero-pad of post-LN)
    {
        int rowbase = pblk*4 - 1;
        #pragma unroll
        for (int i=0;i<9;++i){
            int e = tid + 256*i;                  // 0..2303 exactly
            int px = e/12, sub = e%12;
            int ks = sub >> 2, g2 = sub & 3;
            int lr = px >> 5, col = px & 31;
            int grow = rowbase + lr;
            short8 v = {0,0,0,0,0,0,0,0};
            if ((unsigned)grow < 32u){
                size_t gp = (size_t)(grow*32+col)*96 + ks*32 + 8*g2;
                short8 x8 = *reinterpret_cast<const short8*>(xb2 + gp);
                const float* gpp = gt + gp;
                const float* bpp = bt + gp;
                #pragma unroll
                for (int j=0;j<8;++j){
                    float ag = rr2*gpp[j];
                    v[j] = (short)f2bf(bf2f((u16)x8[j])*ag + (bpp[j] - mu2*ag));
                }
            }
            *reinterpret_cast<short8*>(As + ((size_t)((lr*3+ks)*4+g2)*32 + col)*8) = v;
        }
    }
    {   // stage tap 0 weights (1920 chunks, obk halves contiguous per tap)
        #pragma unroll
        for (int i=0;i<8;++i){
            int c = tid + 256*i;
            if (c < 1920) dma16(Wt + (size_t)c*8, Wbuf + (size_t)(w*64+256*i)*8);
        }
    }

    f32x4 acc[2][10];
    #pragma unroll
    for (int u=0;u<2;++u)
        #pragma unroll
        for (int t=0;t<10;++t) acc[u][t] = (f32x4){0.f,0.f,0.f,0.f};

    for (int tap=0; tap<9; ++tap){
        __syncthreads();                          // Wbuf has tap's weights; As complete
        int dr = tap/3 - 1, dc = tap%3 - 1;

        int lrr = w + 1 + dr;
        int jj0 = cc + dc, jj1 = cc + 16 + dc;
        bool v0 = ((unsigned)jj0 < 32u);
        bool v1 = ((unsigned)jj1 < 32u);

        #pragma unroll
        for (int ks=0; ks<3; ++ks){
            const u16* ab = As + ((size_t)((lrr*3+ks)*4 + gg)*32)*8;
            short8 a0 = {0,0,0,0,0,0,0,0};
            short8 a1 = {0,0,0,0,0,0,0,0};
            if (v0) a0 = *reinterpret_cast<const short8*>(ab + jj0*8);
            if (v1) a1 = *reinterpret_cast<const short8*>(ab + jj1*8);
            #pragma unroll
            for (int t=0; t<10; ++t){
                int fl = (t<5) ? (t*3+ks) : (15 + (t-5)*3 + ks);
                short8 bb = *reinterpret_cast<const short8*>(Wbuf + ((size_t)fl*64 + lane)*8);
                acc[0][t] = __builtin_amdgcn_mfma_f32_16x16x32_bf16(a0, bb, acc[0][t], 0,0,0);
                acc[1][t] = __builtin_amdgcn_mfma_f32_16x16x32_bf16(a1, bb, acc[1][t], 0,0,0);
            }
        }

        __syncthreads();                          // all waves done reading Wbuf
        if (tap < 8){
            const u16* src = Wt + (size_t)(tap+1)*15360;
            #pragma unroll
            for (int i=0;i<8;++i){
                int c = tid + 256*i;
                if (c < 1920) dma16(src + (size_t)c*8, Wbuf + (size_t)(w*64+256*i)*8);
            }
        }
    }
    // after final tap's trailing barrier, As/Wbuf are dead -> Pl overlay is safe

    // ---- C fragments -> LDS params tile Pl[oc][lp], lp = local pixel (pad 132 vs 128)
    #pragma unroll
    for (int u=0;u<2;++u){
        int lp0 = w*32 + u*16 + gg*4;
        #pragma unroll
        for (int t=0;t<10;++t){
            int oc = (t<5) ? (t*16+cc) : (80 + (t-5)*16 + cc);
            if (oc < 156){
                float bv = bias[oc];
                #pragma unroll
                for (int r=0;r<4;++r)
                    SM[oc*132 + lp0 + r] = f2bf(acc[u][t][r] + bv);
            }
        }
    }
    __syncthreads();

    // ---- mixture transform in-block: 768 elems (6 c0 x 128 px), 3 per thread
    float als = a_ls_p[0], abv = a_b_p[0];
    float logsum = 0.f;
    #pragma unroll
    for (int e3=0;e3<3;++e3){
        int e  = tid + 256*e3;
        int c0 = e >> 7, xp = e & 127;
        int pix = pblk*128 + xp;
        int i = pix >> 5, j = pix & 31;

        if (c0 < 3){
            int idx01 = ((b*3+c0)*64 + 2*i)*64 + 2*j+1;
            int idx10 = ((b*3+c0)*64 + 2*i+1)*64 + 2*j;
            out_z[idx01] = z[idx01];
            out_z[idx10] = z[idx10];
        }

        float z0v = (c0<3) ? z[((b*3+c0)*64 + 2*i)*64 + 2*j]
                           : z[((b*3+(c0-3))*64 + 2*i+1)*64 + 2*j+1];
        float a_raw = bf2f(SM[(c0)*132 + xp]);
        float bco   = bf2f(SM[(6+c0)*132 + xp]);
        float lpk[8], muk[8], svk[8];
        float m1 = -1e30f;
        #pragma unroll
        for (int k=0;k<8;++k){
            lpk[k] = bf2f(SM[(12 + k*6 + c0)*132 + xp]);
            muk[k] = bf2f(SM[(60 + k*6 + c0)*132 + xp]);
            svk[k] = bf2f(SM[(108 + k*6 + c0)*132 + xp]);
            m1 = fmaxf(m1, lpk[k]);
        }
        float se = 0.f;
        #pragma unroll
        for (int k=0;k<8;++k) se += __expf(lpk[k]-m1);
        float lse = m1 + __logf(se);
        float xm = 0.f, mt = -1e30f;
        float tk[8];
        #pragma unroll
        for (int k=0;k<8;++k){
            float lpn = lpk[k] - lse;
            float u = (z0v - muk[k]) * __expf(-svk[k]);
            float au = fabsf(u);
            xm += __expf(lpn) * (1.f/(1.f+__expf(-u)));
            float lss = -(au + 2.f*log1pf(__expf(-au)));
            float t2 = lpn - svk[k] + lss;
            tk[k] = t2; mt = fmaxf(mt, t2);
        }
        float se2 = 0.f;
        #pragma unroll
        for (int k=0;k<8;++k) se2 += __expf(tk[k]-mt);
        float logacc = mt + __logf(se2);
        xm = fminf(fmaxf(xm, 1e-6f), 1.f-1e-6f);
        float lx = __logf(xm), l1x = log1pf(-xm);
        logacc += -lx - l1x;
        float aa = tanhf(a_raw)*als + abv;
        float z0n = (lx - l1x)*__expf(aa) + bco;
        logacc += aa;
        int oidx = (c0<3) ? ((b*3+c0)*64 + 2*i)*64 + 2*j
                          : ((b*3+(c0-3))*64 + 2*i+1)*64 + 2*j+1;
        out_z[oidx] = z0n;
        logsum += logacc;
    }

    #pragma unroll
    for (int o=32;o>0;o>>=1) logsum += __shfl_down(logsum, o, 64);
    if (lane==0) red[w] = logsum;
    __syncthreads();
    if (tid==0) atomicAdd(out_log + b, red[0]+red[1]+red[2]+red[3]);
}

extern "C" void kernel_launch(void* const* d_in, const int* in_sizes, int n_in,
                              void* d_out, int out_size, void* d_ws, size_t ws_size,
                              hipStream_t stream)
{
    const float* z     = (const float*)d_in[0];
    const float* logdf = (const float*)d_in[1];
    const float* c1w   = (const float*)d_in[2];
    const float* c1b   = (const float*)d_in[3];
    const float* gw    = (const float*)d_in[4];
    const float* gcb   = (const float*)d_in[5];
    const float* ln1g  = (const float*)d_in[6];
    const float* ln1b  = (const float*)d_in[7];
    const float* qkvw  = (const float*)d_in[8];
    const float* qkvb  = (const float*)d_in[9];
    const float* pw    = (const float*)d_in[10];
    const float* pbb   = (const float*)d_in[11];
    const float* ln2g  = (const float*)d_in[12];
    const float* ln2b  = (const float*)d_in[13];
    const float* c2w   = (const float*)d_in[14];
    const float* c2b   = (const float*)d_in[15];
    const float* als   = (const float*)d_in[16];
    const float* ab    = (const float*)d_in[17];

    float* out_z   = (float*)d_out;
    float* out_log = out_z + 786432;

    // workspace (float units)
    float* ws     = (float*)d_ws;
    u16*   x1b    = (u16*)(ws + 0);            // A: conv1 out bf16; then Qb
    u16*   xg_b   = (u16*)(ws + 3145728);      // B: gated-gconv out bf16 (live thru attnproj)
    u16*   Kf     = (u16*)(ws + 6291456);      // C: K fragment-order
    u16*   Vf     = (u16*)(ws + 9437184);      // D: V fragment-order
    u16*   x2b    = (u16*)(ws + 15728640);     // F: attnproj out bf16 (read by c2mix, LN2 at staging)
    u16*   Qb     = x1b;
    const size_t T = 19660800;
    float* gt1    = ws + T;
    float* bt1    = ws + T + 98304;
    float* gt2    = ws + T + 196608;
    float* bt2    = ws + T + 294912;
    float* part1  = ws + T + 393216;           // 2048
    float* part2  = ws + T + 395264;           // 2048
    u16*   Wg     = (u16*)(ws + T + 397568);   // [9*2][18*512] fragment order
    u16*   W2     = (u16*)(ws + T + 480512);   // [9*2][15*512]
    u16*   Wqkv   = (u16*)(ws + T + 549632);   // [2][27*512]
    u16*   Wproj  = (u16*)(ws + T + 563456);   // [2][18*512]

    k_prep     <<<3417, 256, 0, stream>>>(z, c1w, c1b, gw, c2w, qkvw, pw,
                                          ln1g, ln1b, ln2g, ln2b, logdf,
                                          x1b, Wg, W2, Wqkv, Wproj,
                                          gt1, bt1, gt2, bt2, out_log);
    k_gconv    <<<1024, 256, 0, stream>>>(x1b, Wg, gcb, xg_b, part1);
    k_qkvm     <<<1024, 256, 0, stream>>>(xg_b, gt1, bt1, part1, Wqkv, qkvb, Qb, Kf, Vf);
    k_attnproj <<<512,  256, 0, stream>>>(Qb, Kf, Vf, Wproj, pbb,
                                          xg_b, gt1, bt1, part1, x2b, part2);
    k_c2mix    <<<512,  256, 0, stream>>>(x2b, gt2, bt2, part2, W2, c2b, z, als, ab,
                                          out_z, out_log);
}

// Round 10
// 246.891 us; speedup vs baseline: 1.2806x; 1.2806x over previous
//
#include <hip/hip_runtime.h>
#include <cstdint>
#include <cstddef>

// Problem constants: B=64, C=3, H=W=64, F=96, K=8, h=w=32, C0=6, P=h*w=1024
// params channels: a[0:6) b[6:12) logpi[12:60) mu[60:108) s[108:156)

typedef unsigned short u16;
typedef __attribute__((ext_vector_type(8))) short short8;
typedef __attribute__((ext_vector_type(4))) float f32x4;
typedef __attribute__((ext_vector_type(4))) unsigned int u32x4;

__device__ __forceinline__ float sigm(float x){ return 1.0f/(1.0f+__expf(-x)); }

__device__ __forceinline__ u16 f2bf(float f){
    unsigned int u = __float_as_uint(f);
    u += 0x7fffu + ((u >> 16) & 1u);
    return (u16)(u >> 16);
}
__device__ __forceinline__ float bf2f(u16 v){
    unsigned int u = ((unsigned int)v) << 16;
    return __uint_as_float(u);
}

// async global->LDS DMA, 16B per lane; LDS dest must be wave-uniform base (+lane*16 implied)
__device__ __forceinline__ void dma16(const u16* g, u16* l){
    __builtin_amdgcn_global_load_lds(
        (const __attribute__((address_space(1))) void*)g,
        (__attribute__((address_space(3))) void*)l,
        16, 0, 0);
}

// v_exp_f32 computes 2^x; Q is prescaled by log2(e)/sqrt(96) so this is exp(QK/sqrt(96)).
__device__ __forceinline__ float ex2(float x){
    float r; asm("v_exp_f32 %0, %1" : "=v"(r) : "v"(x)); return r;
}
__device__ __forceinline__ unsigned cvtpk(float lo, float hi){
    unsigned r; asm("v_cvt_pk_bf16_f32 %0, %1, %2" : "=v"(r) : "v"(lo), "v"(hi)); return r;
}
__device__ __forceinline__ void plswap32(unsigned &a, unsigned &b){
    asm("v_permlane32_swap_b32 %0, %1" : "+v"(a), "+v"(b));
}
__device__ __forceinline__ void plswap16(unsigned &a, unsigned &b){
    asm("v_permlane16_swap_b32 %0, %1" : "+v"(a), "+v"(b));
}

// In-register softmax+pack (verified round 1): S[t][r] = scores (q=cc, k=16t+4gg+r).
// Produces PV A-fragments PA[kk]: lane(cc,gg) holds bf16 P[q=cc][k=32kk+8gg+j].
#define SOFTPACK(S, LACC, PA) do { \
    unsigned pk_[4][2]; \
    _Pragma("unroll") \
    for (int t=0;t<4;++t){ \
        float e0 = ex2(S[t][0]); \
        float e1 = ex2(S[t][1]); \
        float e2 = ex2(S[t][2]); \
        float e3 = ex2(S[t][3]); \
        LACC += (e0+e1)+(e2+e3); \
        pk_[t][0] = cvtpk(e0,e1); \
        pk_[t][1] = cvtpk(e2,e3); \
    } \
    _Pragma("unroll") \
    for (int kk=0;kk<2;++kk){ \
        unsigned a0 = pk_[2*kk][0], b0 = pk_[2*kk+1][0]; \
        unsigned a1 = pk_[2*kk][1], b1 = pk_[2*kk+1][1]; \
        plswap32(a0,b0); plswap16(a0,b0); \
        plswap32(a1,b1); plswap16(a1,b1); \
        u32x4 dw_; dw_[0]=a0; dw_[1]=a1; dw_[2]=b0; dw_[3]=b1; \
        PA[kk] = __builtin_bit_cast(short8, dw_); \
    } \
} while(0)

// LN-apply while building an MFMA A-fragment: 8 channels at pixel p, channel base c0.
__device__ __forceinline__ short8 ln_frag(const u16* __restrict__ xg,
    const float* __restrict__ gt, const float* __restrict__ bt,
    int p, int c0, float mu, float rr)
{
    short8 x8 = *reinterpret_cast<const short8*>(xg + (size_t)p*96 + c0);
    const float* gp = gt + (size_t)p*96 + c0;
    const float* bp = bt + (size_t)p*96 + c0;
    short8 o;
    #pragma unroll
    for (int j=0;j<8;++j){
        float ag = rr*gp[j];
        o[j] = (short)f2bf(bf2f((u16)x8[j])*ag + (bp[j] - mu*ag));
    }
    return o;
}

// ---------------- mega-prep: MFMA-conv1 + all weight repacks (fragment-slot linear order,
// DMA-able) + LN transposes + initlog.
__global__ __launch_bounds__(256) void k_prep(
    const float* __restrict__ z, const float* __restrict__ c1w, const float* __restrict__ c1b,
    const float* __restrict__ gw, const float* __restrict__ c2w,
    const float* __restrict__ qkvw, const float* __restrict__ pw,
    const float* __restrict__ ln1g, const float* __restrict__ ln1b,
    const float* __restrict__ ln2g, const float* __restrict__ ln2b,
    const float* __restrict__ logdf,
    u16* __restrict__ x1b,
    u16* __restrict__ Wg, u16* __restrict__ W2,
    u16* __restrict__ Wqkv, u16* __restrict__ Wproj,
    float* __restrict__ gt1, float* __restrict__ bt1,
    float* __restrict__ gt2, float* __restrict__ bt2,
    float* __restrict__ outlog)
{
    int blk = blockIdx.x;
    int tid = threadIdx.x;
    __shared__ float tin[6][6][34];             // conv1 halo tile
    __shared__ __align__(16) u16 Wc[96][72];    // conv1 weights bf16, K padded 54->72
    __shared__ __align__(16) u16 imc[128][72];  // im2col bf16

    if (blk < 512){
        // ---- conv1 as MFMA im2col GEMM: 128 px x 96 oc, K=54 padded to 64
        int b  = blk >> 3;
        int pg = blk & 7;
        int r0 = pg*4;
        for (int e = tid; e < 96*72; e += 256){
            int oc = e/72, k = e%72;
            Wc[oc][k] = (k < 54) ? f2bf(c1w[oc*54 + k]) : (u16)0;
        }
        for (int idx = tid; idx < 6*6*34; idx += 256){
            int c = idx/204, rem = idx%204;
            int rr = rem/34, q = rem%34;
            int ii = r0 - 1 + rr, jj = q - 1;
            float v = 0.f;
            if ((unsigned)ii < 32u && (unsigned)jj < 32u){
                if (c < 3) v = z[((b*3+c)*64 + 2*ii)*64 + (2*jj+1)];        // p01
                else       v = z[((b*3+(c-3))*64 + (2*ii+1))*64 + 2*jj];    // p10
            }
            tin[c][rr][q] = v;
        }
        __syncthreads();
        for (int e = tid; e < 128*72; e += 256){
            int px = e/72, k = e%72;
            float v = 0.f;
            if (k < 54){
                int c = k/9, rr = (k%9)/3, dcc = k%3;
                v = tin[c][(px>>5)+rr][(px&31)+dcc];
            }
            imc[px][k] = f2bf(v);
        }
        __syncthreads();

        int w = tid >> 6, lane = tid & 63;
        int cc = lane & 15, gg = lane >> 4;
        f32x4 acc[2][6];
        #pragma unroll
        for (int u=0;u<2;++u)
            #pragma unroll
            for (int t=0;t<6;++t) acc[u][t] = (f32x4){0.f,0.f,0.f,0.f};

        #pragma unroll
        for (int ks=0; ks<2; ++ks){
            short8 a0 = *reinterpret_cast<const short8*>(&imc[w*32 + cc     ][ks*32 + 8*gg]);
            short8 a1 = *reinterpret_cast<const short8*>(&imc[w*32 + 16 + cc][ks*32 + 8*gg]);
            #pragma unroll
            for (int t=0; t<6; ++t){
                short8 bb = *reinterpret_cast<const short8*>(&Wc[t*16+cc][ks*32 + 8*gg]);
                acc[0][t] = __builtin_amdgcn_mfma_f32_16x16x32_bf16(a0, bb, acc[0][t], 0,0,0);
                acc[1][t] = __builtin_amdgcn_mfma_f32_16x16x32_bf16(a1, bb, acc[1][t], 0,0,0);
            }
        }

        #pragma unroll
        for (int u=0;u<2;++u){
            int p0 = pg*128 + w*32 + u*16 + gg*4;
            #pragma unroll
            for (int t=0;t<6;++t){
                int oc = t*16+cc;
                float bv = c1b[oc];
                #pragma unroll
                for (int r=0;r<4;++r)
                    x1b[((size_t)(b*1024) + p0 + r)*96 + oc] = f2bf(acc[u][t][r] + bv);
            }
        }
    } else if (blk < 1160){
        // gconv weights, fragment-slot order: idx = ((tap*2+obk)*18 + t*3+ks)*512 + lane*8 + j
        int idx = (blk-512)*256 + tid;                // < 165888
        int j = idx & 7;
        int lane = (idx >> 3) & 63;
        int fo = idx >> 9;
        int frag = fo % 18;
        int tob = fo / 18;
        int obk = tob & 1, tap = tob >> 1;
        int t = frag/3, ks = frag%3;
        int cc = lane & 15, gg = lane >> 4;
        int ocp = obk*96 + t*16 + cc;                 // packed-paired row
        int r2 = ocp%96, isB = r2/48, i2 = r2%48;
        int oc = (ocp/96)*48 + i2 + isB*96;
        int ic = ks*32 + 8*gg + j;
        Wg[idx] = f2bf(gw[(size_t)(oc*96+ic)*9 + tap]);
    } else if (blk < 1700){
        // conv2 weights: idx = ((tap*2+obk)*15 + t*3+ks)*512 + lane*8 + j
        int idx = (blk-1160)*256 + tid;               // < 138240
        int j = idx & 7;
        int lane = (idx >> 3) & 63;
        int fo = idx >> 9;
        int frag = fo % 15;
        int tob = fo / 15;
        int obk = tob & 1, tap = tob >> 1;
        int t = frag/3, ks = frag%3;
        int cc = lane & 15, gg = lane >> 4;
        int oc = obk*80 + t*16 + cc;
        int ic = ks*32 + 8*gg + j;
        W2[idx] = (oc < 156) ? f2bf(c2w[(size_t)(oc*96+ic)*9 + tap]) : (u16)0;
    } else if (blk < 1808){
        // qkv weights: idx = (obk*27 + t*3+ks)*512 + lane*8 + j
        int idx = (blk-1700)*256 + tid;               // < 27648
        int j = idx & 7;
        int lane = (idx >> 3) & 63;
        int fo = idx >> 9;
        int frag = fo % 27;
        int obk = fo / 27;
        int t = frag/3, ks = frag%3;
        int cc = lane & 15, gg = lane >> 4;
        int n = obk*144 + t*16 + cc;
        int ic = ks*32 + 8*gg + j;
        Wqkv[idx] = f2bf(qkvw[(size_t)n*96 + ic]);
    } else if (blk < 1880){
        // proj weights (packed-paired): idx = (obk*18 + t*3+ks)*512 + lane*8 + j
        int idx = (blk-1808)*256 + tid;               // < 18432
        int j = idx & 7;
        int lane = (idx >> 3) & 63;
        int fo = idx >> 9;
        int frag = fo % 18;
        int obk = fo / 18;
        int t = frag/3, ks = frag%3;
        int cc = lane & 15, gg = lane >> 4;
        int ocp = obk*96 + t*16 + cc;
        int r2 = ocp%96, isB = r2/48, i2 = r2%48;
        int oc = obk*48 + i2 + isB*96;
        int ic = ks*32 + 8*gg + j;
        Wproj[idx] = f2bf(pw[(size_t)oc*96 + ic]);
    } else if (blk < 2264){
        int idx = (blk-1880)*256 + tid;               // < 98304
        int c = idx >> 10, p = idx & 1023;
        gt1[p*96 + c] = ln1g[idx];
    } else if (blk < 2648){
        int idx = (blk-2264)*256 + tid;
        int c = idx >> 10, p = idx & 1023;
        bt1[p*96 + c] = ln1b[idx];
    } else if (blk < 3032){
        int idx = (blk-2648)*256 + tid;
        int c = idx >> 10, p = idx & 1023;
        gt2[p*96 + c] = ln2g[idx];
    } else if (blk < 3416){
        int idx = (blk-3032)*256 + tid;
        int c = idx >> 10, p = idx & 1023;
        bt2[p*96 + c] = ln2b[idx];
    } else {
        if (tid < 64) outlog[tid] = logdf[tid];
    }
}

// ---------------- gated conv: OC split across 2 blocks (paired), grid 1024 = 4/CU.
__global__ __launch_bounds__(256,4) void k_gconv(const u16* __restrict__ Xpb,
    const u16* __restrict__ Wt, const float* __restrict__ bias,
    u16* __restrict__ outb, float* __restrict__ partials)
{
    int blk  = blockIdx.x;
    int obk  = blk & 1;
    int pblk = (blk >> 1) & 7;
    int b    = blk >> 4;
    int tid  = threadIdx.x;
    int w = tid >> 6, lane = tid & 63;
    int cc = lane & 15, gg = lane >> 4;

    __shared__ __align__(16) u16 Ws[2][9216];     // 18 frags * 512 per tap
    __shared__ float red[8];

    f32x4 acc[2][6];
    #pragma unroll
    for (int u=0;u<2;++u)
        #pragma unroll
        for (int t=0;t<6;++t) acc[u][t] = (f32x4){0.f,0.f,0.f,0.f};

    int base = pblk*128 + w*32;
    int ia = base >> 5;
    const u16* xb = Xpb + (size_t)b*1024*96;

    {   // stage tap 0
        const u16* src = Wt + (size_t)obk*9216;
        #pragma unroll
        for (int i=0;i<5;++i){
            int c = tid + 256*i;
            if (c < 1152) dma16(src + (size_t)c*8, Ws[0] + (size_t)(w*64+256*i)*8);
        }
    }

    for (int tap=0; tap<9; ++tap){
        __syncthreads();                          // drains vmcnt -> Ws[tap&1] complete
        if (tap < 8){
            const u16* src = Wt + (size_t)((tap+1)*2 + obk)*9216;
            int nb = (tap+1)&1;
            #pragma unroll
            for (int i=0;i<5;++i){
                int c = tid + 256*i;
                if (c < 1152) dma16(src + (size_t)c*8, Ws[nb] + (size_t)(w*64+256*i)*8);
            }
        }
        const u16* Wc = Ws[tap&1];
        int dr = tap/3 - 1, dc = tap%3 - 1;

        int ii = ia + dr;
        int jj0 = cc + dc, jj1 = cc + 16 + dc;
        bool rv = ((unsigned)ii < 32u);
        bool v0 = rv && ((unsigned)jj0 < 32u);
        bool v1 = rv && ((unsigned)jj1 < 32u);
        const u16* ar0 = xb + (ptrdiff_t)(ii*32 + jj0)*96 + 8*gg;
        const u16* ar1 = xb + (ptrdiff_t)(ii*32 + jj1)*96 + 8*gg;

        #pragma unroll
        for (int ks=0; ks<3; ++ks){
            short8 a0 = {0,0,0,0,0,0,0,0};
            short8 a1 = {0,0,0,0,0,0,0,0};
            if (v0) a0 = *reinterpret_cast<const short8*>(ar0 + ks*32);
            if (v1) a1 = *reinterpret_cast<const short8*>(ar1 + ks*32);
            #pragma unroll
            for (int t=0; t<6; ++t){
                short8 bb = *reinterpret_cast<const short8*>(Wc + ((size_t)(t*3+ks)*64 + lane)*8);
                acc[0][t] = __builtin_amdgcn_mfma_f32_16x16x32_bf16(a0, bb, acc[0][t], 0,0,0);
                acc[1][t] = __builtin_amdgcn_mfma_f32_16x16x32_bf16(a1, bb, acc[1][t], 0,0,0);
            }
        }
    }

    float s = 0.f, ssq = 0.f;
    #pragma unroll
    for (int u=0;u<2;++u){
        int p0 = base + u*16 + gg*4;
        #pragma unroll
        for (int t=0;t<3;++t){
            int ocA = obk*48 + t*16+cc;
            float ba = bias[ocA], bbv = bias[ocA+96];
            #pragma unroll
            for (int r=0;r<4;++r){
                float res = bf2f(Xpb[((size_t)b*1024 + p0+r)*96 + ocA]);
                float va = acc[u][t][r]   + ba;
                float vb = acc[u][t+3][r] + bbv;
                float v = res + va*sigm(vb);
                outb[((size_t)b*1024 + p0+r)*96 + ocA] = f2bf(v);
                s += v; ssq += v*v;
            }
        }
    }
    #pragma unroll
    for (int o=32;o>0;o>>=1){ s += __shfl_down(s,o,64); ssq += __shfl_down(ssq,o,64); }
    if (lane==0){ red[w]=s; red[4+w]=ssq; }
    __syncthreads();
    if (tid==0){
        int slot = b*16 + pblk*2 + obk;
        partials[slot*2+0] = red[0]+red[1]+red[2]+red[3];
        partials[slot*2+1] = red[4]+red[5]+red[6]+red[7];
    }
}

// ---------------- LN apply (LN2), flat coalesced elementwise.
__global__ __launch_bounds__(256) void k_lne(const u16* __restrict__ xb,
    const float* __restrict__ gt, const float* __restrict__ bt,
    const float* __restrict__ partials, u16* __restrict__ out)
{
    int b = blockIdx.x / 48, rem = blockIdx.x % 48;
    float s=0.f, ss=0.f;
    #pragma unroll
    for (int i=0;i<16;++i){ s += partials[(b*16+i)*2]; ss += partials[(b*16+i)*2+1]; }
    float mu = s/98304.f;
    float r = rsqrtf(ss/98304.f - mu*mu + 1e-5f);

    int e8 = rem*256 + threadIdx.x;
    size_t base = (size_t)b*98304 + (size_t)e8*8;
    short8 x8 = *reinterpret_cast<const short8*>(xb + base);
    const float* gp = gt + e8*8;
    const float* bp = bt + e8*8;
    short8 o8;
    #pragma unroll
    for (int i=0;i<8;++i)
        o8[i] = (short)f2bf((bf2f((u16)x8[i]) - mu)*r*gp[i] + bp[i]);
    *reinterpret_cast<short8*>(out + base) = o8;
}

// ---------------- qkv with inline LN1: OC 288 split across 2 blocks of 144, grid 1024.
__global__ __launch_bounds__(256,4) void k_qkvm(const u16* __restrict__ Xg,
    const float* __restrict__ gt, const float* __restrict__ bt,
    const float* __restrict__ part,
    const u16* __restrict__ Wt, const float* __restrict__ bias,
    u16* __restrict__ Qb, u16* __restrict__ Kf, u16* __restrict__ Vf)
{
    int blk  = blockIdx.x;
    int obk  = blk & 1;
    int pblk = (blk >> 1) & 7;
    int b    = blk >> 4;
    int tid  = threadIdx.x;
    int w = tid >> 6, lane = tid & 63;
    int cc = lane & 15, gg = lane >> 4;
    const float scale = 0.14724445f;   // log2(e)/sqrt(96)

    __shared__ __align__(16) u16 Ws[13824];       // 27 frags * 512
    {
        const u16* src = Wt + (size_t)obk*13824;
        #pragma unroll
        for (int i=0;i<7;++i){
            int c = tid + 256*i;
            if (c < 1728) dma16(src + (size_t)c*8, Ws + (size_t)(w*64+256*i)*8);
        }
    }

    float sS=0.f, sQ=0.f;
    #pragma unroll
    for (int i=0;i<16;++i){ sS += part[(b*16+i)*2]; sQ += part[(b*16+i)*2+1]; }
    float mu = sS/98304.f;
    float rr = rsqrtf(sQ/98304.f - mu*mu + 1e-5f);

    f32x4 acc[2][9];
    #pragma unroll
    for (int u=0;u<2;++u)
        #pragma unroll
        for (int t=0;t<9;++t) acc[u][t] = (f32x4){0.f,0.f,0.f,0.f};

    int base = pblk*128 + w*32;
    const u16* xg = Xg + (size_t)b*1024*96;
    __syncthreads();                              // Ws DMA complete

    #pragma unroll
    for (int ks=0; ks<3; ++ks){
        int c0 = ks*32 + 8*gg;
        short8 a0 = ln_frag(xg, gt, bt, base+cc,    c0, mu, rr);
        short8 a1 = ln_frag(xg, gt, bt, base+cc+16, c0, mu, rr);
        #pragma unroll
        for (int t=0; t<9; ++t){
            short8 bb = *reinterpret_cast<const short8*>(Ws + ((size_t)(t*3+ks)*64 + lane)*8);
            acc[0][t] = __builtin_amdgcn_mfma_f32_16x16x32_bf16(a0, bb, acc[0][t], 0,0,0);
            acc[1][t] = __builtin_amdgcn_mfma_f32_16x16x32_bf16(a1, bb, acc[1][t], 0,0,0);
        }
    }

    #pragma unroll
    for (int u=0;u<2;++u){
        int p0 = base + u*16 + gg*4;
        #pragma unroll
        for (int t=0;t<9;++t){
            int n = obk*144 + t*16+cc;
            float bv = bias[n];
            #pragma unroll
            for (int r=0;r<4;++r){
                int p = p0 + r;
                float av = acc[u][t][r] + bv;
                if (n < 96){
                    Qb[((size_t)(b*1024+p))*96 + n] = f2bf(av*scale);
                } else if (n < 192){
                    int f = n-96;
                    int jt = p>>6, t16 = (p>>4)&3, ccs = p&15;
                    int ks = f>>5, ggs = (f>>3)&3, j = f&7;
                    Kf[(size_t)(b*16+jt)*6144 + (size_t)(((t16*3+ks)*4+ggs)*16+ccs)*8 + j] = f2bf(av);
                } else {
                    int f = n-192;
                    int jt = p>>6, kl = p&63;
                    int kk = kl>>5, ggs = (kl>>3)&3, j = kl&7;
                    int ft = f>>4, ccs = f&15;
                    Vf[(size_t)(b*16+jt)*6144 + (size_t)(((ft*2+kk)*4+ggs)*16+ccs)*8 + j] = f2bf(av);
                }
            }
        }
    }
}

// ---------------- FUSED flash attention + proj: attn (R4 structure, unchanged) keeps O in
// registers; O -> LDS tile (per-wave private rows, no barrier needed); Wproj DMA'd into the
// dead K-buffer region; proj GEMM from LDS + LN1-residual epilogue writes x2b + part2.
// Deletes the 25 MB Ob round-trip + one dispatch. LDS union 73.7 KB -> 2 blocks/CU.
__global__ __launch_bounds__(256,2) void k_attnproj(const u16* __restrict__ Qb,
    const u16* __restrict__ Kf, const u16* __restrict__ Vf,
    const u16* __restrict__ Wpg, const float* __restrict__ pbias,
    const u16* __restrict__ Xg, const float* __restrict__ gt, const float* __restrict__ bt,
    const float* __restrict__ part1,
    u16* __restrict__ outb, float* __restrict__ partials)
{
    int qt = blockIdx.x >> 6;       // 0..7
    int b  = blockIdx.x & 63;
    int tid = threadIdx.x;
    int w  = tid >> 6;
    int lane = tid & 63;
    int cc = lane & 15;
    int gg = lane >> 4;

    __shared__ __align__(16) u16 SM[36864];   // 73728 B: phase1 Ks[3][6144]+Vs[3][6144];
                                              // phase2 Wp[18432] + Ot[128][104]
    __shared__ float red[16];

    u16* Ksb = SM;              // [3][6144]
    u16* Vsb = SM + 18432;      // [3][6144]
    u16* Wp  = SM;              // phase 2 overlay (Ks region)
    u16* Ot  = SM + 18432;      // phase 2 overlay (Vs region): 128 rows x 104

    // LN1 stats (needed in phase-2 epilogue; cheap, do up front)
    float sS=0.f, sQ=0.f;
    #pragma unroll
    for (int i=0;i<16;++i){ sS += part1[(b*16+i)*2]; sQ += part1[(b*16+i)*2+1]; }
    float mu1 = sS/98304.f;
    float rr1 = rsqrtf(sQ/98304.f - mu1*mu1 + 1e-5f);

    int q0 = qt*128 + w*32;

    short8 qf[2][3];
    {
        const u16* qr0 = Qb + ((size_t)(b*1024 + q0 + cc))*96;
        #pragma unroll
        for (int ks=0; ks<3; ++ks){
            qf[0][ks] = *reinterpret_cast<const short8*>(qr0 + ks*32 + 8*gg);
            qf[1][ks] = *reinterpret_cast<const short8*>(qr0 + (size_t)16*96 + ks*32 + 8*gg);
        }
    }

    f32x4 Oacc[2][6];
    #pragma unroll
    for (int u=0;u<2;++u)
        #pragma unroll
        for (int ft=0; ft<6; ++ft) Oacc[u][ft] = (f32x4){0.f,0.f,0.f,0.f};
    float l_acc[2] = {0.f, 0.f};

    const u16* Kb0 = Kf + (size_t)(b*16)*6144;
    const u16* Vb0 = Vf + (size_t)(b*16)*6144;

    #pragma unroll
    for (int i=0;i<3;++i){
        size_t c8 = (size_t)(tid + 256*i)*8;
        size_t l8 = (size_t)(w*64 + 256*i)*8;
        dma16(Kb0 + c8, Ksb + l8);
        dma16(Vb0 + c8, Vsb + l8);
    }
    #pragma unroll
    for (int i=0;i<3;++i){
        size_t c8 = (size_t)(6144 + (tid + 256*i)*8);
        size_t l8 = (size_t)(w*64 + 256*i)*8;
        dma16(Kb0 + c8, Ksb + 6144 + l8);
        dma16(Vb0 + c8, Vsb + 6144 + l8);
    }

    for (int jt=0; jt<16; ++jt){
        if (jt < 15) asm volatile("s_waitcnt vmcnt(6)" ::: "memory");
        else         asm volatile("s_waitcnt vmcnt(0)" ::: "memory");
        __builtin_amdgcn_s_barrier();
        __builtin_amdgcn_sched_barrier(0);

        if (jt < 14){
            const u16* kn = Kb0 + (size_t)(jt+2)*6144;
            const u16* vn = Vb0 + (size_t)(jt+2)*6144;
            u16* kd = Ksb + (size_t)((jt+2)%3)*6144;
            u16* vd = Vsb + (size_t)((jt+2)%3)*6144;
            #pragma unroll
            for (int i=0;i<3;++i){
                size_t c8 = (size_t)(tid + 256*i)*8;
                size_t l8 = (size_t)(w*64 + 256*i)*8;
                dma16(kn + c8, kd + l8);
                dma16(vn + c8, vd + l8);
            }
        }

        const u16* Kc = Ksb + (size_t)(jt%3)*6144;
        const u16* Vc = Vsb + (size_t)(jt%3)*6144;

        f32x4 S0[4], S1[4];
        #pragma unroll
        for (int t=0;t<4;++t){ S0[t] = (f32x4){0.f,0.f,0.f,0.f}; S1[t] = (f32x4){0.f,0.f,0.f,0.f}; }

        __builtin_amdgcn_s_setprio(1);
        #pragma unroll
        for (int ks=0; ks<3; ++ks){
            #pragma unroll
            for (int t=0; t<4; ++t){
                short8 kb = *reinterpret_cast<const short8*>(Kc + ((t*3+ks)*64 + lane)*8);
                S0[t] = __builtin_amdgcn_mfma_f32_16x16x32_bf16(kb, qf[0][ks], S0[t], 0,0,0);
                S1[t] = __builtin_amdgcn_mfma_f32_16x16x32_bf16(kb, qf[1][ks], S1[t], 0,0,0);
            }
        }
        __builtin_amdgcn_s_setprio(0);

        short8 pa0[2], pa1[2];
        SOFTPACK(S0, l_acc[0], pa0);
        SOFTPACK(S1, l_acc[1], pa1);

        __builtin_amdgcn_s_setprio(1);
        #pragma unroll
        for (int kk=0; kk<2; ++kk){
            #pragma unroll
            for (int ft=0; ft<6; ++ft){
                short8 vb = *reinterpret_cast<const short8*>(Vc + ((ft*2+kk)*64 + lane)*8);
                Oacc[0][ft] = __builtin_amdgcn_mfma_f32_16x16x32_bf16(pa0[kk], vb, Oacc[0][ft], 0,0,0);
                Oacc[1][ft] = __builtin_amdgcn_mfma_f32_16x16x32_bf16(pa1[kk], vb, Oacc[1][ft], 0,0,0);
            }
        }
        __builtin_amdgcn_s_setprio(0);
    }

    // ---- phase transition: all waves done reading K/V regions
    __syncthreads();

    // Wproj DMA into Ks region: 2304 * 16B = 36864 B, 9 dma16/thread, exact
    #pragma unroll
    for (int i=0;i<9;++i){
        int c = tid + 256*i;
        dma16(Wpg + (size_t)c*8, Wp + (size_t)(w*64+256*i)*8);
    }

    // O (x 1/l) -> Ot[row=local pixel][col=channel], rows w*32..+31 are wave-private
    #pragma unroll
    for (int u=0;u<2;++u){
        float lv = l_acc[u];
        lv += __shfl_xor(lv, 16, 64);
        lv += __shfl_xor(lv, 32, 64);
        float linv[4];
        #pragma unroll
        for (int r=0;r<4;++r) linv[r] = 1.0f / __shfl(lv, 4*gg + r, 64);
        #pragma unroll
        for (int ft=0; ft<6; ++ft)
            #pragma unroll
            for (int r=0; r<4; ++r)
                Ot[(size_t)(w*32 + u*16 + 4*gg + r)*104 + ft*16 + cc]
                    = f2bf(Oacc[u][ft][r]*linv[r]);
    }

    __syncthreads();                               // drains vmcnt+lgkm: Wp + Ot complete

    // ---- proj GEMM from LDS: 128 px x 192 ocp (both halves), acc[2][12]
    f32x4 pacc[2][12];
    #pragma unroll
    for (int u=0;u<2;++u)
        #pragma unroll
        for (int t=0;t<12;++t) pacc[u][t] = (f32x4){0.f,0.f,0.f,0.f};

    #pragma unroll
    for (int ks=0; ks<3; ++ks){
        short8 a0 = *reinterpret_cast<const short8*>(Ot + (size_t)(w*32 + cc     )*104 + ks*32 + 8*gg);
        short8 a1 = *reinterpret_cast<const short8*>(Ot + (size_t)(w*32 + cc + 16)*104 + ks*32 + 8*gg);
        #pragma unroll
        for (int t2=0; t2<12; ++t2){
            int obk = t2/6, tl = t2%6;
            short8 bb = *reinterpret_cast<const short8*>(Wp + ((size_t)(obk*18 + tl*3 + ks)*64 + lane)*8);
            pacc[0][t2] = __builtin_amdgcn_mfma_f32_16x16x32_bf16(a0, bb, pacc[0][t2], 0,0,0);
            pacc[1][t2] = __builtin_amdgcn_mfma_f32_16x16x32_bf16(a1, bb, pacc[1][t2], 0,0,0);
        }
    }

    // ---- epilogue: gated residual + LN1-inline, per-obk partial sums (same part2 layout)
    const u16* resb = Xg + (size_t)b*1024*96;
    float s0=0.f, q0s=0.f, s1=0.f, q1s=0.f;
    #pragma unroll
    for (int u=0;u<2;++u){
        int p0 = qt*128 + w*32 + u*16 + gg*4;
        #pragma unroll
        for (int obk=0;obk<2;++obk){
            #pragma unroll
            for (int tl=0;tl<3;++tl){
                int ocA = obk*48 + tl*16 + cc;
                float ba = pbias[ocA], bbv = pbias[ocA+96];
                #pragma unroll
                for (int r=0;r<4;++r){
                    int pl = p0 + r;
                    float ga = pacc[u][obk*6+tl][r]   + ba;
                    float gb = pacc[u][obk*6+tl+3][r] + bbv;
                    float xv = bf2f(resb[(size_t)pl*96 + ocA]);
                    float res = (xv - mu1)*rr1*gt[(size_t)pl*96 + ocA] + bt[(size_t)pl*96 + ocA];
                    float v = res + ga * sigm(gb);
                    outb[((size_t)b*1024 + pl)*96 + ocA] = f2bf(v);
                    if (obk==0){ s0 += v; q0s += v*v; } else { s1 += v; q1s += v*v; }
                }
            }
        }
    }
    #pragma unroll
    for (int o=32;o>0;o>>=1){
        s0 += __shfl_down(s0,o,64);  q0s += __shfl_down(q0s,o,64);
        s1 += __shfl_down(s1,o,64);  q1s += __shfl_down(q1s,o,64);
    }
    if (lane==0){ red[w*4+0]=s0; red[w*4+1]=q0s; red[w*4+2]=s1; red[w*4+3]=q1s; }
    __syncthreads();
    if (tid==0){
        int slot = b*16 + qt*2;
        partials[(size_t)slot*2+0]     = red[0]+red[4]+red[8]+red[12];
        partials[(size_t)slot*2+1]     = red[1]+red[5]+red[9]+red[13];
        partials[(size_t)(slot+1)*2+0] = red[2]+red[6]+red[10]+red[14];
        partials[(size_t)(slot+1)*2+1] = red[3]+red[7]+red[11]+red[15];
    }
}

// ---------------- FUSED conv2 + mixture (round-5 verified version): one block = (b, pblk),
// all 156 oc for 128 pixels; C staged in LDS; mixture in-block. Reads the LN2-applied xln2b.
__global__ __launch_bounds__(256,2) void k_c2mix(const u16* __restrict__ Xpb,
    const u16* __restrict__ Wt, const float* __restrict__ bias,
    const float* __restrict__ z, const float* __restrict__ a_ls_p,
    const float* __restrict__ a_b_p, float* __restrict__ out_z, float* __restrict__ out_log)
{
    int blk  = blockIdx.x;
    int pblk = blk & 7;
    int b    = blk >> 3;
    int tid  = threadIdx.x;
    int w = tid >> 6, lane = tid & 63;
    int cc = lane & 15, gg = lane >> 4;

    __shared__ __align__(16) u16 SM[30720];   // union: Ws dbuf 2x15360 u16 | Pl[156][132]
    __shared__ float red[4];

    f32x4 acc[2][10];
    #pragma unroll
    for (int u=0;u<2;++u)
        #pragma unroll
        for (int t=0;t<10;++t) acc[u][t] = (f32x4){0.f,0.f,0.f,0.f};

    int base = pblk*128 + w*32;
    int ia = base >> 5;
    const u16* xb = Xpb + (size_t)b*1024*96;

    {   // stage tap 0: both obk chunks are contiguous in W2's [tap][obk][15frag] layout
        #pragma unroll
        for (int i=0;i<8;++i){
            int c = tid + 256*i;
            if (c < 1920) dma16(Wt + (size_t)c*8, SM + (size_t)(w*64+256*i)*8);
        }
    }

    for (int tap=0; tap<9; ++tap){
        __syncthreads();                          // drains vmcnt -> current buffer complete
        if (tap < 8){
            const u16* src = Wt + (size_t)(tap+1)*15360;
            u16* dst = SM + (size_t)((tap+1)&1)*15360;
            #pragma unroll
            for (int i=0;i<8;++i){
                int c = tid + 256*i;
                if (c < 1920) dma16(src + (size_t)c*8, dst + (size_t)(w*64+256*i)*8);
            }
        }
        const u16* Wc = SM + (size_t)(tap&1)*15360;
        int dr = tap/3 - 1, dc = tap%3 - 1;

        int ii = ia + dr;
        int jj0 = cc + dc, jj1 = cc + 16 + dc;
        bool rv = ((unsigned)ii < 32u);
        bool v0 = rv && ((unsigned)jj0 < 32u);
        bool v1 = rv && ((unsigned)jj1 < 32u);
        const u16* ar0 = xb + (ptrdiff_t)(ii*32 + jj0)*96 + 8*gg;
        const u16* ar1 = xb + (ptrdiff_t)(ii*32 + jj1)*96 + 8*gg;

        #pragma unroll
        for (int ks=0; ks<3; ++ks){
            short8 a0 = {0,0,0,0,0,0,0,0};
            short8 a1 = {0,0,0,0,0,0,0,0};
            if (v0) a0 = *reinterpret_cast<const short8*>(ar0 + ks*32);
            if (v1) a1 = *reinterpret_cast<const short8*>(ar1 + ks*32);
            #pragma unroll
            for (int t=0; t<10; ++t){
                int fl = (t<5) ? (t*3+ks) : (15 + (t-5)*3 + ks);
                short8 bb = *reinterpret_cast<const short8*>(Wc + ((size_t)fl*64 + lane)*8);
                acc[0][t] = __builtin_amdgcn_mfma_f32_16x16x32_bf16(a0, bb, acc[0][t], 0,0,0);
                acc[1][t] = __builtin_amdgcn_mfma_f32_16x16x32_bf16(a1, bb, acc[1][t], 0,0,0);
            }
        }
    }

    // ---- C fragments -> LDS params tile Pl[oc][lp], lp = local pixel (pad 132 vs 128)
    __syncthreads();                              // all waves done reading Ws[0]
    #pragma unroll
    for (int u=0;u<2;++u){
        int lp0 = w*32 + u*16 + gg*4;
        #pragma unroll
        for (int t=0;t<10;++t){
            int oc = (t<5) ? (t*16+cc) : (80 + (t-5)*16 + cc);
            if (oc < 156){
                float bv = bias[oc];
                #pragma unroll
                for (int r=0;r<4;++r)
                    SM[oc*132 + lp0 + r] = f2bf(acc[u][t][r] + bv);
            }
        }
    }
    __syncthreads();

    // ---- mixture transform in-block: 768 elems (6 c0 x 128 px), 3 per thread
    float als = a_ls_p[0], abv = a_b_p[0];
    float logsum = 0.f;
    #pragma unroll
    for (int e3=0;e3<3;++e3){
        int e  = tid + 256*e3;
        int c0 = e >> 7, xp = e & 127;
        int pix = pblk*128 + xp;
        int i = pix >> 5, j = pix & 31;

        if (c0 < 3){
            int idx01 = ((b*3+c0)*64 + 2*i)*64 + 2*j+1;
            int idx10 = ((b*3+c0)*64 + 2*i+1)*64 + 2*j;
            out_z[idx01] = z[idx01];
            out_z[idx10] = z[idx10];
        }

        float z0v = (c0<3) ? z[((b*3+c0)*64 + 2*i)*64 + 2*j]
                           : z[((b*3+(c0-3))*64 + 2*i+1)*64 + 2*j+1];
        float a_raw = bf2f(SM[(c0)*132 + xp]);
        float bco   = bf2f(SM[(6+c0)*132 + xp]);
        float lpk[8], muk[8], svk[8];
        float m1 = -1e30f;
        #pragma unroll
        for (int k=0;k<8;++k){
            lpk[k] = bf2f(SM[(12 + k*6 + c0)*132 + xp]);
            muk[k] = bf2f(SM[(60 + k*6 + c0)*132 + xp]);
            svk[k] = bf2f(SM[(108 + k*6 + c0)*132 + xp]);
            m1 = fmaxf(m1, lpk[k]);
        }
        float se = 0.f;
        #pragma unroll
        for (int k=0;k<8;++k) se += __expf(lpk[k]-m1);
        float lse = m1 + __logf(se);
        float xm = 0.f, mt = -1e30f;
        float tk[8];
        #pragma unroll
        for (int k=0;k<8;++k){
            float lpn = lpk[k] - lse;
            float u = (z0v - muk[k]) * __expf(-svk[k]);
            float au = fabsf(u);
            xm += __expf(lpn) * (1.f/(1.f+__expf(-u)));
            float lss = -(au + 2.f*log1pf(__expf(-au)));
            float t2 = lpn - svk[k] + lss;
            tk[k] = t2; mt = fmaxf(mt, t2);
        }
        float se2 = 0.f;
        #pragma unroll
        for (int k=0;k<8;++k) se2 += __expf(tk[k]-mt);
        float logacc = mt + __logf(se2);
        xm = fminf(fmaxf(xm, 1e-6f), 1.f-1e-6f);
        float lx = __logf(xm), l1x = log1pf(-xm);
        logacc += -lx - l1x;
        float aa = tanhf(a_raw)*als + abv;
        float z0n = (lx - l1x)*__expf(aa) + bco;
        logacc += aa;
        int oidx = (c0<3) ? ((b*3+c0)*64 + 2*i)*64 + 2*j
                          : ((b*3+(c0-3))*64 + 2*i+1)*64 + 2*j+1;
        out_z[oidx] = z0n;
        logsum += logacc;
    }

    #pragma unroll
    for (int o=32;o>0;o>>=1) logsum += __shfl_down(logsum, o, 64);
    if (lane==0) red[w] = logsum;
    __syncthreads();
    if (tid==0) atomicAdd(out_log + b, red[0]+red[1]+red[2]+red[3]);
}

extern "C" void kernel_launch(void* const* d_in, const int* in_sizes, int n_in,
                              void* d_out, int out_size, void* d_ws, size_t ws_size,
                              hipStream_t stream)
{
    const float* z     = (const float*)d_in[0];
    const float* logdf = (const float*)d_in[1];
    const float* c1w   = (const float*)d_in[2];
    const float* c1b   = (const float*)d_in[3];
    const float* gw    = (const float*)d_in[4];
    const float* gcb   = (const float*)d_in[5];
    const float* ln1g  = (const float*)d_in[6];
    const float* ln1b  = (const float*)d_in[7];
    const float* qkvw  = (const float*)d_in[8];
    const float* qkvb  = (const float*)d_in[9];
    const float* pw    = (const float*)d_in[10];
    const float* pbb   = (const float*)d_in[11];
    const float* ln2g  = (const float*)d_in[12];
    const float* ln2b  = (const float*)d_in[13];
    const float* c2w   = (const float*)d_in[14];
    const float* c2b   = (const float*)d_in[15];
    const float* als   = (const float*)d_in[16];
    const float* ab    = (const float*)d_in[17];

    float* out_z   = (float*)d_out;
    float* out_log = out_z + 786432;

    // workspace (float units)
    float* ws     = (float*)d_ws;
    u16*   x1b    = (u16*)(ws + 0);            // A: conv1 out bf16; then Qb
    u16*   xg_b   = (u16*)(ws + 3145728);      // B: gated-gconv out bf16 (live thru attnproj)
    u16*   Kf     = (u16*)(ws + 6291456);      // C: K fragment-order; then xln2b
    u16*   Vf     = (u16*)(ws + 9437184);      // D: V fragment-order
    u16*   x2b    = (u16*)(ws + 15728640);     // F: attnproj out bf16
    u16*   Qb     = x1b;
    u16*   xln2b  = Kf;                        // C reuse (Kf dead after attnproj)
    const size_t T = 19660800;
    float* gt1    = ws + T;
    float* bt1    = ws + T + 98304;
    float* gt2    = ws + T + 196608;
    float* bt2    = ws + T + 294912;
    float* part1  = ws + T + 393216;           // 2048
    float* part2  = ws + T + 395264;           // 2048
    u16*   Wg     = (u16*)(ws + T + 397568);   // [9*2][18*512] fragment order
    u16*   W2     = (u16*)(ws + T + 480512);   // [9*2][15*512]
    u16*   Wqkv   = (u16*)(ws + T + 549632);   // [2][27*512]
    u16*   Wproj  = (u16*)(ws + T + 563456);   // [2][18*512]

    k_prep     <<<3417, 256, 0, stream>>>(z, c1w, c1b, gw, c2w, qkvw, pw,
                                          ln1g, ln1b, ln2g, ln2b, logdf,
                                          x1b, Wg, W2, Wqkv, Wproj,
                                          gt1, bt1, gt2, bt2, out_log);
    k_gconv    <<<1024, 256, 0, stream>>>(x1b, Wg, gcb, xg_b, part1);
    k_qkvm     <<<1024, 256, 0, stream>>>(xg_b, gt1, bt1, part1, Wqkv, qkvb, Qb, Kf, Vf);
    k_attnproj <<<512,  256, 0, stream>>>(Qb, Kf, Vf, Wproj, pbb,
                                          xg_b, gt1, bt1, part1, x2b, part2);
    k_lne      <<<3072, 256, 0, stream>>>(x2b, gt2, bt2, part2, xln2b);
    k_c2mix    <<<512,  256, 0, stream>>>(xln2b, W2, c2b, z, als, ab, out_z, out_log);
}